// Round 19
// baseline (210.855 us; speedup 1.0000x reference)
//
#include <hip/hip_runtime.h>
#include <hip/hip_bf16.h>
#include <stdint.h>

#define EMB 768
#define HEADS 12
#define BATCH 8
#define SEQ 1024
#define HD 64
#define M_ROWS (BATCH * SEQ)   /* 8192 */
#define QKV_COLS (3 * EMB)     /* 2304 */

typedef __attribute__((ext_vector_type(8))) short short8;
typedef __attribute__((ext_vector_type(4))) float f32x4;

__device__ __forceinline__ unsigned short f2bf(float x) {
    union { float f; unsigned u; } v; v.f = x;
    unsigned r = v.u + 0x7FFFu + ((v.u >> 16) & 1u);
    return (unsigned short)(r >> 16);
}
__device__ __forceinline__ float bf2f(unsigned short h) {
    union { unsigned u; float f; } v; v.u = ((unsigned)h) << 16;
    return v.f;
}
__device__ __forceinline__ float truncbf(float x) {
    return __uint_as_float(__float_as_uint(x) & 0xFFFF0000u);
}
__device__ __forceinline__ uint32_t packtr(float a, float b) {   // lo16=tr(a), hi16=tr(b)
    return (__float_as_uint(a) >> 16) | (__float_as_uint(b) & 0xFFFF0000u);
}
__device__ __forceinline__ uint32_t cvtpk(float a, float b) {    // lo16=bf16rn(a), hi16=bf16rn(b)
    uint32_t r;
    asm("v_cvt_pk_bf16_f32 %0, %1, %2" : "=v"(r) : "v"(a), "v"(b));
    return r;
}

#define MFMA16(a, b, c) __builtin_amdgcn_mfma_f32_16x16x32_bf16((a), (b), (c), 0, 0, 0)

// ---------------------------------------------------------------------------
// Prep (r15..r18-verified): split + transpose + COLUMN-PERMUTE Wqkv into
// Wht/Wlt bf16 [col'][k], col' = which*768 + h*64 + d. Q/K: trunc hi/lo;
// V: RN in Wht. Epilogue inverse map: src = 192h + 3d + which.
// ---------------------------------------------------------------------------
__global__ __launch_bounds__(256)
void split_tw(const float* __restrict__ W,
              unsigned short* __restrict__ Wht, unsigned short* __restrict__ Wlt)
{
    __shared__ unsigned short Th[64][72], Tl[64][72];
    const int tid = threadIdx.x;
    const int ct = blockIdx.x * 64;    // source col tile (36)
    const int kt = blockIdx.y * 64;    // k tile (12)

    #pragma unroll
    for (int p = 0; p < 4; ++p) {
        int idx = (p << 8) + tid;
        int k = idx >> 4, c4 = (idx & 15) << 2;
        f32x4 v = *reinterpret_cast<const f32x4*>(W + (size_t)(kt + k) * QKV_COLS + ct + c4);
        #pragma unroll
        for (int j = 0; j < 4; ++j) {
            const int whichj = (ct + c4 + j) % 3;
            if (whichj == 2) {
                Th[c4 + j][k] = f2bf(v[j]);            // RN for V
                Tl[c4 + j][k] = 0;
            } else {
                Th[c4 + j][k] = (unsigned short)(__float_as_uint(v[j]) >> 16);
                Tl[c4 + j][k] = (unsigned short)(__float_as_uint(v[j] - truncbf(v[j])) >> 16);
            }
        }
    }
    __syncthreads();
    #pragma unroll
    for (int p = 0; p < 2; ++p) {
        int idx = (p << 8) + tid;
        int c = idx >> 3, k8 = (idx & 7) << 3;
        const int s = ct + c;                          // source col
        const int dst = (s % 3) * 768 + (s / 192) * 64 + (s % 192) / 3;
        *reinterpret_cast<uint4*>(Wht + (size_t)dst * EMB + kt + k8) =
            *reinterpret_cast<const uint4*>(&Th[c][k8]);
        *reinterpret_cast<uint4*>(Wlt + (size_t)dst * EMB + kt + k8) =
            *reinterpret_cast<const uint4*>(&Tl[c][k8]);
    }
}

// ---------------------------------------------------------------------------
// Q/K GEMM, BK=64 (12 K-iters, half the barriers of r18's BK=32): cols
// 0..1535 of permuted W. A = X inline trunc-split; B = straight uint4
// copies; always 3-term MFMA. (256,2): 256-VGPR budget (r14 lesson);
// LDS 73.7KB -> 2 blocks/CU (same occupancy as BK=32 had).
// ---------------------------------------------------------------------------
__global__ __launch_bounds__(256, 2)
void gemm_qk(const float* __restrict__ X,
             const unsigned short* __restrict__ Wht, const unsigned short* __restrict__ Wlt,
             const float* __restrict__ bias,
             unsigned short* __restrict__ Qh, unsigned short* __restrict__ Ql,
             unsigned short* __restrict__ Kh, unsigned short* __restrict__ Kl)
{
    __shared__ unsigned short Ash[128][72], Asl[128][72];  // [row][k], 64+8 pad
    __shared__ unsigned short Bsh[128][72], Bsl[128][72];  // [col'][k]

    const int tid  = threadIdx.x;
    const int wave = tid >> 6, lane = tid & 63;
    const int lr = lane & 15, lg = lane >> 4;
    const int wr = (wave >> 1) * 64, wc = (wave & 1) * 64;
    const int m0 = blockIdx.y * 128;
    const int c0 = blockIdx.x * 128;          // 0..1408

    const f32x4 fzero = {0.f, 0.f, 0.f, 0.f};
    f32x4 acc[4][4];
    #pragma unroll
    for (int m = 0; m < 4; ++m)
        #pragma unroll
        for (int n = 0; n < 4; ++n) acc[m][n] = fzero;

    for (int k0 = 0; k0 < EMB; k0 += 64) {
        // A tile: 128 rows x 64 k, inline trunc-split
        #pragma unroll
        for (int p = 0; p < 8; ++p) {
            int idx = (p << 8) + tid;
            int row = idx >> 4, kc = (idx & 15) << 2;
            f32x4 v = *reinterpret_cast<const f32x4*>(X + (size_t)(m0 + row) * EMB + k0 + kc);
            float l0 = v[0] - truncbf(v[0]), l1 = v[1] - truncbf(v[1]);
            float l2 = v[2] - truncbf(v[2]), l3 = v[3] - truncbf(v[3]);
            uint2 hw = { packtr(v[0], v[1]), packtr(v[2], v[3]) };
            uint2 lw = { packtr(l0, l1), packtr(l2, l3) };
            *reinterpret_cast<uint2*>(&Ash[row][kc]) = hw;
            *reinterpret_cast<uint2*>(&Asl[row][kc]) = lw;
        }
        // B tile: 128 cols x 64 k, straight uint4 copies
        #pragma unroll
        for (int p = 0; p < 4; ++p) {
            int idx = (p << 8) + tid;
            int row = idx >> 3, kc = (idx & 7) << 3;
            const size_t boff = (size_t)(c0 + row) * EMB + k0 + kc;
            *reinterpret_cast<uint4*>(&Bsh[row][kc]) = *reinterpret_cast<const uint4*>(Wht + boff);
            *reinterpret_cast<uint4*>(&Bsl[row][kc]) = *reinterpret_cast<const uint4*>(Wlt + boff);
        }
        __syncthreads();

        #pragma unroll
        for (int kk = 0; kk < 2; ++kk) {
            short8 ah[4], al[4], bh[4], bl[4];
            #pragma unroll
            for (int m = 0; m < 4; ++m) {
                ah[m] = *reinterpret_cast<const short8*>(&Ash[wr + m * 16 + lr][kk * 32 + (lg << 3)]);
                al[m] = *reinterpret_cast<const short8*>(&Asl[wr + m * 16 + lr][kk * 32 + (lg << 3)]);
            }
            #pragma unroll
            for (int n = 0; n < 4; ++n) {
                bh[n] = *reinterpret_cast<const short8*>(&Bsh[wc + n * 16 + lr][kk * 32 + (lg << 3)]);
                bl[n] = *reinterpret_cast<const short8*>(&Bsl[wc + n * 16 + lr][kk * 32 + (lg << 3)]);
            }
            #pragma unroll
            for (int m = 0; m < 4; ++m)
                #pragma unroll
                for (int n = 0; n < 4; ++n) {
                    acc[m][n] = MFMA16(ah[m], bh[n], acc[m][n]);
                    acc[m][n] = MFMA16(ah[m], bl[n], acc[m][n]);
                    acc[m][n] = MFMA16(al[m], bh[n], acc[m][n]);
                }
        }
        __syncthreads();
    }

    const int which = c0 / 768;               // block-uniform
    unsigned short* __restrict__ Ph = (which == 0) ? Qh : Kh;
    unsigned short* __restrict__ Pl = (which == 0) ? Ql : Kl;
    #pragma unroll
    for (int m = 0; m < 4; ++m) {
        #pragma unroll
        for (int n = 0; n < 4; ++n) {
            const int colg = c0 + wc + n * 16 + lr;
            const int hd = colg - which * 768;
            const int h  = hd >> 6;
            const int dd = hd & 63;
            const float bv = bias[192 * h + 3 * dd + which];
            const int rowg0 = m0 + wr + m * 16 + (lg << 2);
            const int bi = rowg0 >> 10, ni0 = rowg0 & (SEQ - 1);
            const int bhid = bi * HEADS + h;
            #pragma unroll
            for (int j = 0; j < 4; ++j) {
                const float val = acc[m][n][j] + bv;
                const size_t oidx = ((size_t)bhid * SEQ + ni0 + j) * HD + dd;
                const uint32_t uv = __float_as_uint(val);
                Ph[oidx] = (unsigned short)(uv >> 16);
                Pl[oidx] = (unsigned short)(__float_as_uint(
                    val - __uint_as_float(uv & 0xFFFF0000u)) >> 16);
            }
        }
    }
}

// ---------------------------------------------------------------------------
// V GEMM (r16..r18-verified, branch-free, 1-term): cols 1536..2303.
// ---------------------------------------------------------------------------
__global__ __launch_bounds__(256, 2)
void gemm_v(const float* __restrict__ X,
            const unsigned short* __restrict__ Wht,
            const float* __restrict__ bias,
            unsigned short* __restrict__ Vt)
{
    __shared__ unsigned short Ash[128][40];
    __shared__ unsigned short Bsh[128][40];

    const int tid  = threadIdx.x;
    const int wave = tid >> 6, lane = tid & 63;
    const int lr = lane & 15, lg = lane >> 4;
    const int wr = (wave >> 1) * 64, wc = (wave & 1) * 64;
    const int m0 = blockIdx.y * 128;
    const int c0 = blockIdx.x * 128;          // 0..640 (local to V region)

    const f32x4 fzero = {0.f, 0.f, 0.f, 0.f};
    f32x4 acc[4][4];
    #pragma unroll
    for (int m = 0; m < 4; ++m)
        #pragma unroll
        for (int n = 0; n < 4; ++n) acc[m][n] = fzero;

    for (int k0 = 0; k0 < EMB; k0 += 32) {
        #pragma unroll
        for (int p = 0; p < 4; ++p) {
            int idx = (p << 8) + tid;
            int row = idx >> 3, kc = (idx & 7) << 2;
            f32x4 v = *reinterpret_cast<const f32x4*>(X + (size_t)(m0 + row) * EMB + k0 + kc);
            uint2 hw = { packtr(v[0], v[1]), packtr(v[2], v[3]) };
            *reinterpret_cast<uint2*>(&Ash[row][kc]) = hw;
        }
        #pragma unroll
        for (int p = 0; p < 2; ++p) {
            int idx = (p << 8) + tid;
            int row = idx >> 2, kc = (idx & 3) << 3;
            const size_t boff = (size_t)(1536 + c0 + row) * EMB + k0 + kc;
            *reinterpret_cast<uint4*>(&Bsh[row][kc]) = *reinterpret_cast<const uint4*>(Wht + boff);
        }
        __syncthreads();

        short8 a[4], b[4];
        #pragma unroll
        for (int m = 0; m < 4; ++m)
            a[m] = *reinterpret_cast<const short8*>(&Ash[wr + m * 16 + lr][lg << 3]);
        #pragma unroll
        for (int n = 0; n < 4; ++n)
            b[n] = *reinterpret_cast<const short8*>(&Bsh[wc + n * 16 + lr][lg << 3]);
        #pragma unroll
        for (int m = 0; m < 4; ++m)
            #pragma unroll
            for (int n = 0; n < 4; ++n)
                acc[m][n] = MFMA16(a[m], b[n], acc[m][n]);
        __syncthreads();
    }

    #pragma unroll
    for (int m = 0; m < 4; ++m) {
        #pragma unroll
        for (int n = 0; n < 4; ++n) {
            const int hd = c0 + wc + n * 16 + lr;     // 0..767
            const int h  = hd >> 6;
            const int dd = hd & 63;
            const float bv = bias[192 * h + 3 * dd + 2];
            const int rowg0 = m0 + wr + m * 16 + (lg << 2);
            const int bi = rowg0 >> 10, ni0 = rowg0 & (SEQ - 1);
            const int bhid = bi * HEADS + h;
            const float v0 = acc[m][n][0] + bv, v1 = acc[m][n][1] + bv;
            const float v2 = acc[m][n][2] + bv, v3 = acc[m][n][3] + bv;
            uint2 w = { (uint32_t)f2bf(v0) | ((uint32_t)f2bf(v1) << 16),
                        (uint32_t)f2bf(v2) | ((uint32_t)f2bf(v3) << 16) };
            *reinterpret_cast<uint2*>(Vt + ((size_t)bhid * HD + dd) * SEQ + ni0) = w;
        }
    }
}

// ---------------------------------------------------------------------------
// Flash attention, QBLK=128: each wave owns TWO 16-row q-groups (A at
// qt*128+wave*16, B at +64). 768 blocks = exactly 3/CU (no tail); K/V
// staging amortized 2x; both QK MFMA batches issue before softmax-A so
// softmax VALU overlaps in-flight MFMAs. Register-prefetch staging (r17),
// cvt_pk + defer-max + max3 softmax (r18). Core layouts r12..r18-verified.
// ---------------------------------------------------------------------------
__global__ __launch_bounds__(256, 3)
void attn_fused(const unsigned short* __restrict__ Qh, const unsigned short* __restrict__ Ql,
                const unsigned short* __restrict__ Kh, const unsigned short* __restrict__ Kl,
                const unsigned short* __restrict__ Vt,
                unsigned short* __restrict__ Ob)
{
    __shared__ unsigned short Vs[64][72];         // V^T tile: [d][key]
    __shared__ unsigned short Ksh[64][72];        // K hi tile: [key][d]
    __shared__ unsigned short Ksl[64][72];        // K lo tile: [key][d]
    __shared__ unsigned short Plds[2][4][16][72]; // P per group/wave: [qrow][key]

    const int tid  = threadIdx.x;
    const int wave = tid >> 6, lane = tid & 63;
    const int lr = lane & 15, lg = lane >> 4;

    // bijective XCD swizzle: 768 blocks = 8 XCD * 96; same-bh blocks co-locate
    const int bid = blockIdx.x;
    const int lid = (bid & 7) * 96 + (bid >> 3);
    const int qt = lid & 7;             // 0..7
    const int bh = lid >> 3;            // 0..95
    const int b = bh / HEADS, h = bh % HEADS;

    const size_t base = (size_t)bh * SEQ * HD;
    const unsigned short* Qhb = Qh + base;
    const unsigned short* Qlb = Ql + base;
    const unsigned short* Khb = Kh + base;
    const unsigned short* Klb = Kl + base;
    const unsigned short* Vtb = Vt + base;      // [HD][SEQ]

    const int qA = qt * 128 + wave * 16;
    const int qB = qA + 64;

    short8 qhA[2], qlA[2], qhB[2], qlB[2];
    #pragma unroll
    for (int kk = 0; kk < 2; ++kk) {
        const size_t offA = (size_t)(qA + lr) * HD + kk * 32 + (lg << 3);
        const size_t offB = (size_t)(qB + lr) * HD + kk * 32 + (lg << 3);
        qhA[kk] = *reinterpret_cast<const short8*>(Qhb + offA);
        qlA[kk] = *reinterpret_cast<const short8*>(Qlb + offA);
        qhB[kk] = *reinterpret_cast<const short8*>(Qhb + offB);
        qlB[kk] = *reinterpret_cast<const short8*>(Qlb + offB);
    }

    const int r0 = tid >> 3, cs = (tid & 7) << 3;
    const int r1 = r0 + 32;

    uint4 vr0 = *reinterpret_cast<const uint4*>(Vtb + (size_t)r0 * SEQ + cs);
    uint4 vr1 = *reinterpret_cast<const uint4*>(Vtb + (size_t)r1 * SEQ + cs);
    uint4 kh0 = *reinterpret_cast<const uint4*>(Khb + (size_t)r0 * HD + cs);
    uint4 kh1 = *reinterpret_cast<const uint4*>(Khb + (size_t)r1 * HD + cs);
    uint4 kl0 = *reinterpret_cast<const uint4*>(Klb + (size_t)r0 * HD + cs);
    uint4 kl1 = *reinterpret_cast<const uint4*>(Klb + (size_t)r1 * HD + cs);

    float mA = -1.0e30f, lA = 0.f, mB = -1.0e30f, lB = 0.f;
    f32x4 oaccA[4], oaccB[4];
    const f32x4 fzero = {0.f, 0.f, 0.f, 0.f};
    #pragma unroll
    for (int d = 0; d < 4; ++d) { oaccA[d] = fzero; oaccB[d] = fzero; }

    for (int t = 0; t < SEQ / 64; ++t) {
        __syncthreads();
        *reinterpret_cast<uint4*>(&Vs[r0][cs])  = vr0;
        *reinterpret_cast<uint4*>(&Vs[r1][cs])  = vr1;
        *reinterpret_cast<uint4*>(&Ksh[r0][cs]) = kh0;
        *reinterpret_cast<uint4*>(&Ksh[r1][cs]) = kh1;
        *reinterpret_cast<uint4*>(&Ksl[r0][cs]) = kl0;
        *reinterpret_cast<uint4*>(&Ksl[r1][cs]) = kl1;
        __syncthreads();

        if (t < SEQ / 64 - 1) {
            const int kb = (t + 1) * 64;
            vr0 = *reinterpret_cast<const uint4*>(Vtb + (size_t)r0 * SEQ + kb + cs);
            vr1 = *reinterpret_cast<const uint4*>(Vtb + (size_t)r1 * SEQ + kb + cs);
            kh0 = *reinterpret_cast<const uint4*>(Khb + (size_t)(kb + r0) * HD + cs);
            kh1 = *reinterpret_cast<const uint4*>(Khb + (size_t)(kb + r1) * HD + cs);
            kl0 = *reinterpret_cast<const uint4*>(Klb + (size_t)(kb + r0) * HD + cs);
            kl1 = *reinterpret_cast<const uint4*>(Klb + (size_t)(kb + r1) * HD + cs);
        }

        // QK^T for BOTH groups first (softmax-A VALU overlaps sB's MFMAs)
        f32x4 sA[4], sB[4];
        #pragma unroll
        for (int n = 0; n < 4; ++n) { sA[n] = fzero; sB[n] = fzero; }
        #pragma unroll
        for (int n = 0; n < 4; ++n) {
            #pragma unroll
            for (int kk = 0; kk < 2; ++kk) {
                const short8 kh = *reinterpret_cast<const short8*>(&Ksh[n * 16 + lr][kk * 32 + (lg << 3)]);
                const short8 kl = *reinterpret_cast<const short8*>(&Ksl[n * 16 + lr][kk * 32 + (lg << 3)]);
                sA[n] = MFMA16(kh, qhA[kk], sA[n]);
                sA[n] = MFMA16(kh, qlA[kk], sA[n]);
                sA[n] = MFMA16(kl, qhA[kk], sA[n]);
                sB[n] = MFMA16(kh, qhB[kk], sB[n]);
                sB[n] = MFMA16(kh, qlB[kk], sB[n]);
                sB[n] = MFMA16(kl, qhB[kk], sB[n]);
            }
        }

        // ---- softmax + PV, group A ----
        {
            float a0 = fmaxf(fmaxf(sA[0][0], sA[0][1]), sA[0][2]);
            float a1 = fmaxf(fmaxf(sA[0][3], sA[1][0]), sA[1][1]);
            float a2 = fmaxf(fmaxf(sA[1][2], sA[1][3]), sA[2][0]);
            float a3 = fmaxf(fmaxf(sA[2][1], sA[2][2]), sA[2][3]);
            float a4 = fmaxf(fmaxf(sA[3][0], sA[3][1]), sA[3][2]);
            float tmax = fmaxf(fmaxf(fmaxf(a0, a1), a2), fmaxf(fmaxf(a3, a4), sA[3][3]));
            tmax = fmaxf(tmax, __shfl_xor(tmax, 16));
            tmax = fmaxf(tmax, __shfl_xor(tmax, 32));
            if (!__all(tmax <= mA + 8.0f)) {
                const float mnew = fmaxf(mA, tmax);
                const float corr = __expf(mA - mnew);
                mA = mnew;
                lA *= corr;
                #pragma unroll
                for (int j = 0; j < 4; ++j) {
                    const float cj = __shfl(corr, (lg << 2) + j);
                    oaccA[0][j] *= cj; oaccA[1][j] *= cj;
                    oaccA[2][j] *= cj; oaccA[3][j] *= cj;
                }
            }
            float psum = 0.f;
            #pragma unroll
            for (int n = 0; n < 4; ++n) {
                const float p0 = __expf(sA[n][0] - mA), p1 = __expf(sA[n][1] - mA);
                const float p2 = __expf(sA[n][2] - mA), p3 = __expf(sA[n][3] - mA);
                psum += (p0 + p1) + (p2 + p3);
                uint2 w = { cvtpk(p0, p1), cvtpk(p2, p3) };
                *reinterpret_cast<uint2*>(&Plds[0][wave][lr][n * 16 + (lg << 2)]) = w;
            }
            psum += __shfl_xor(psum, 16);
            psum += __shfl_xor(psum, 32);
            lA += psum;
            #pragma unroll
            for (int kk = 0; kk < 2; ++kk) {
                const short8 ap = *reinterpret_cast<const short8*>(&Plds[0][wave][lr][kk * 32 + (lg << 3)]);
                #pragma unroll
                for (int d = 0; d < 4; ++d) {
                    const short8 bv = *reinterpret_cast<const short8*>(&Vs[d * 16 + lr][kk * 32 + (lg << 3)]);
                    oaccA[d] = MFMA16(ap, bv, oaccA[d]);
                }
            }
        }

        // ---- softmax + PV, group B ----
        {
            float a0 = fmaxf(fmaxf(sB[0][0], sB[0][1]), sB[0][2]);
            float a1 = fmaxf(fmaxf(sB[0][3], sB[1][0]), sB[1][1]);
            float a2 = fmaxf(fmaxf(sB[1][2], sB[1][3]), sB[2][0]);
            float a3 = fmaxf(fmaxf(sB[2][1], sB[2][2]), sB[2][3]);
            float a4 = fmaxf(fmaxf(sB[3][0], sB[3][1]), sB[3][2]);
            float tmax = fmaxf(fmaxf(fmaxf(a0, a1), a2), fmaxf(fmaxf(a3, a4), sB[3][3]));
            tmax = fmaxf(tmax, __shfl_xor(tmax, 16));
            tmax = fmaxf(tmax, __shfl_xor(tmax, 32));
            if (!__all(tmax <= mB + 8.0f)) {
                const float mnew = fmaxf(mB, tmax);
                const float corr = __expf(mB - mnew);
                mB = mnew;
                lB *= corr;
                #pragma unroll
                for (int j = 0; j < 4; ++j) {
                    const float cj = __shfl(corr, (lg << 2) + j);
                    oaccB[0][j] *= cj; oaccB[1][j] *= cj;
                    oaccB[2][j] *= cj; oaccB[3][j] *= cj;
                }
            }
            float psum = 0.f;
            #pragma unroll
            for (int n = 0; n < 4; ++n) {
                const float p0 = __expf(sB[n][0] - mB), p1 = __expf(sB[n][1] - mB);
                const float p2 = __expf(sB[n][2] - mB), p3 = __expf(sB[n][3] - mB);
                psum += (p0 + p1) + (p2 + p3);
                uint2 w = { cvtpk(p0, p1), cvtpk(p2, p3) };
                *reinterpret_cast<uint2*>(&Plds[1][wave][lr][n * 16 + (lg << 2)]) = w;
            }
            psum += __shfl_xor(psum, 16);
            psum += __shfl_xor(psum, 32);
            lB += psum;
            #pragma unroll
            for (int kk = 0; kk < 2; ++kk) {
                const short8 ap = *reinterpret_cast<const short8*>(&Plds[1][wave][lr][kk * 32 + (lg << 3)]);
                #pragma unroll
                for (int d = 0; d < 4; ++d) {
                    const short8 bv = *reinterpret_cast<const short8*>(&Vs[d * 16 + lr][kk * 32 + (lg << 3)]);
                    oaccB[d] = MFMA16(ap, bv, oaccB[d]);
                }
            }
        }
    }

    const float rs = 0.036084391824351615f;  // 1/sqrt(768)
    #pragma unroll
    for (int j = 0; j < 4; ++j) {
        const float ljA = __shfl(lA, (lg << 2) + j);
        const float ljB = __shfl(lB, (lg << 2) + j);
        const float scA = rs / ljA;
        const float scB = rs / ljB;
        const int qa = qA + (lg << 2) + j;
        const int qb = qB + (lg << 2) + j;
        #pragma unroll
        for (int d = 0; d < 4; ++d) {
            Ob[((size_t)b * SEQ + qa) * EMB + h * HD + d * 16 + lr] = f2bf(oaccA[d][j] * scA);
            Ob[((size_t)b * SEQ + qb) * EMB + h * HD + d * 16 + lr] = f2bf(oaccB[d][j] * scB);
        }
    }
}

// ---------------------------------------------------------------------------
// Proj GEMM (r16..r18-verified): Ob bf16 @ W_proj (fp32->bf16 RN) + b -> fp32.
// ---------------------------------------------------------------------------
__global__ __launch_bounds__(256, 4)
void gemm_proj(const unsigned short* __restrict__ A, const float* __restrict__ W,
               const float* __restrict__ bias, float* __restrict__ Out)
{
    __shared__ unsigned short As[128][40];
    __shared__ unsigned short Bs[128][40];

    const int tid  = threadIdx.x;
    const int wave = tid >> 6, lane = tid & 63;
    const int lr = lane & 15, lg = lane >> 4;
    const int wr = (wave >> 1) * 64, wc = (wave & 1) * 64;
    const int m0 = blockIdx.y * 128;
    const int c0 = blockIdx.x * 128;

    const f32x4 fzero = {0.f, 0.f, 0.f, 0.f};
    f32x4 acc[4][4];
    #pragma unroll
    for (int m = 0; m < 4; ++m)
        #pragma unroll
        for (int n = 0; n < 4; ++n) acc[m][n] = fzero;

    const int kgB = tid & 7, cgB = tid >> 3;

    for (int k0 = 0; k0 < EMB; k0 += 32) {
        #pragma unroll
        for (int p = 0; p < 2; ++p) {
            int idx = (p << 8) + tid;
            int row = idx >> 2, kc = (idx & 3) << 3;
            uint4 v = *reinterpret_cast<const uint4*>(A + (size_t)(m0 + row) * EMB + k0 + kc);
            *reinterpret_cast<uint4*>(&As[row][kc]) = v;
        }
        {
            f32x4 v[4];
            #pragma unroll
            for (int i = 0; i < 4; ++i)
                v[i] = *reinterpret_cast<const f32x4*>(
                    W + (size_t)(k0 + kgB * 4 + i) * EMB + c0 + cgB * 4);
            #pragma unroll
            for (int j = 0; j < 4; ++j) {
                uint2 w = { (uint32_t)f2bf(v[0][j]) | ((uint32_t)f2bf(v[1][j]) << 16),
                            (uint32_t)f2bf(v[2][j]) | ((uint32_t)f2bf(v[3][j]) << 16) };
                *reinterpret_cast<uint2*>(&Bs[cgB * 4 + j][kgB * 4]) = w;
            }
        }
        __syncthreads();

        short8 a[4], b[4];
        #pragma unroll
        for (int m = 0; m < 4; ++m)
            a[m] = *reinterpret_cast<const short8*>(&As[wr + m * 16 + lr][lg << 3]);
        #pragma unroll
        for (int n = 0; n < 4; ++n)
            b[n] = *reinterpret_cast<const short8*>(&Bs[wc + n * 16 + lr][lg << 3]);
        #pragma unroll
        for (int m = 0; m < 4; ++m)
            #pragma unroll
            for (int n = 0; n < 4; ++n)
                acc[m][n] = MFMA16(a[m], b[n], acc[m][n]);
        __syncthreads();
    }

    #pragma unroll
    for (int m = 0; m < 4; ++m) {
        #pragma unroll
        for (int n = 0; n < 4; ++n) {
            const int colg = c0 + wc + n * 16 + lr;
            const float bv = bias[colg];
            #pragma unroll
            for (int j = 0; j < 4; ++j) {
                const int rowg = m0 + wr + m * 16 + (lg << 2) + j;
                Out[(size_t)rowg * EMB + colg] = acc[m][n][j] + bv;   // fp32 out
            }
        }
    }
}

// ---------------------------------------------------------------------------
extern "C" void kernel_launch(void* const* d_in, const int* in_sizes, int n_in,
                              void* d_out, int out_size, void* d_ws, size_t ws_size,
                              hipStream_t stream)
{
    const float* x     = (const float*)d_in[0];
    const float* Wqkv  = (const float*)d_in[1];
    const float* bqkv  = (const float*)d_in[2];
    const float* Wproj = (const float*)d_in[3];
    const float* bproj = (const float*)d_in[4];
    float* out = (float*)d_out;    // reference output dtype = float32

    const size_t NQ = (size_t)BATCH * HEADS * SEQ * HD;   // 6291456
    const size_t NW = (size_t)EMB * QKV_COLS;             // 1769472

    unsigned short* Qh = (unsigned short*)d_ws;
    unsigned short* Ql = Qh + NQ;
    unsigned short* Kh = Ql + NQ;
    unsigned short* Kl = Kh + NQ;
    unsigned short* Vt = Kl + NQ;                         // [B,H,D,N]
    unsigned short* Ob = Vt + NQ;                         // total 75.5 MB (proven)

    // W prep scratch in the Ob region (7.1 MB of 12.6): consumed by the two
    // QKV GEMMs, later overwritten by attn_fused (sequential stream).
    unsigned short* Wht = Ob;
    unsigned short* Wlt = Wht + NW;

    split_tw<<<dim3(QKV_COLS / 64, EMB / 64), 256, 0, stream>>>(Wqkv, Wht, Wlt);
    gemm_qk<<<dim3(1536 / 128, M_ROWS / 128), 256, 0, stream>>>(
        x, Wht, Wlt, bqkv, Qh, Ql, Kh, Kl);
    gemm_v<<<dim3(768 / 128, M_ROWS / 128), 256, 0, stream>>>(
        x, Wht, bqkv, Vt);
    attn_fused<<<dim3(8 * BATCH * HEADS), 256, 0, stream>>>(Qh, Ql, Kh, Kl, Vt, Ob);
    gemm_proj<<<dim3(EMB / 128, M_ROWS / 128), 256, 0, stream>>>(
        Ob, Wproj, bproj, out);
}

// Round 20
// 198.171 us; speedup vs baseline: 1.0640x; 1.0640x over previous
//
#include <hip/hip_runtime.h>
#include <hip/hip_bf16.h>
#include <stdint.h>

#define EMB 768
#define HEADS 12
#define BATCH 8
#define SEQ 1024
#define HD 64
#define M_ROWS (BATCH * SEQ)   /* 8192 */
#define QKV_COLS (3 * EMB)     /* 2304 */

typedef __attribute__((ext_vector_type(8))) short short8;
typedef __attribute__((ext_vector_type(4))) float f32x4;

__device__ __forceinline__ unsigned short f2bf(float x) {
    union { float f; unsigned u; } v; v.f = x;
    unsigned r = v.u + 0x7FFFu + ((v.u >> 16) & 1u);
    return (unsigned short)(r >> 16);
}
__device__ __forceinline__ float bf2f(unsigned short h) {
    union { unsigned u; float f; } v; v.u = ((unsigned)h) << 16;
    return v.f;
}
__device__ __forceinline__ float truncbf(float x) {
    return __uint_as_float(__float_as_uint(x) & 0xFFFF0000u);
}
__device__ __forceinline__ uint32_t packtr(float a, float b) {   // lo16=tr(a), hi16=tr(b)
    return (__float_as_uint(a) >> 16) | (__float_as_uint(b) & 0xFFFF0000u);
}
__device__ __forceinline__ uint32_t cvtpk(float a, float b) {    // lo16=bf16rn(a), hi16=bf16rn(b)
    uint32_t r;
    asm("v_cvt_pk_bf16_f32 %0, %1, %2" : "=v"(r) : "v"(a), "v"(b));
    return r;
}

#define MFMA16(a, b, c) __builtin_amdgcn_mfma_f32_16x16x32_bf16((a), (b), (c), 0, 0, 0)

// ---------------------------------------------------------------------------
// Prep (r15..r19-verified): split + transpose + COLUMN-PERMUTE Wqkv into
// Wht/Wlt bf16 [col'][k], col' = which*768 + h*64 + d. Q/K: trunc hi/lo;
// V: RN in Wht. Epilogue inverse map: src = 192h + 3d + which.
// ---------------------------------------------------------------------------
__global__ __launch_bounds__(256)
void split_tw(const float* __restrict__ W,
              unsigned short* __restrict__ Wht, unsigned short* __restrict__ Wlt)
{
    __shared__ unsigned short Th[64][72], Tl[64][72];
    const int tid = threadIdx.x;
    const int ct = blockIdx.x * 64;    // source col tile (36)
    const int kt = blockIdx.y * 64;    // k tile (12)

    #pragma unroll
    for (int p = 0; p < 4; ++p) {
        int idx = (p << 8) + tid;
        int k = idx >> 4, c4 = (idx & 15) << 2;
        f32x4 v = *reinterpret_cast<const f32x4*>(W + (size_t)(kt + k) * QKV_COLS + ct + c4);
        #pragma unroll
        for (int j = 0; j < 4; ++j) {
            const int whichj = (ct + c4 + j) % 3;
            if (whichj == 2) {
                Th[c4 + j][k] = f2bf(v[j]);            // RN for V
                Tl[c4 + j][k] = 0;
            } else {
                Th[c4 + j][k] = (unsigned short)(__float_as_uint(v[j]) >> 16);
                Tl[c4 + j][k] = (unsigned short)(__float_as_uint(v[j] - truncbf(v[j])) >> 16);
            }
        }
    }
    __syncthreads();
    #pragma unroll
    for (int p = 0; p < 2; ++p) {
        int idx = (p << 8) + tid;
        int c = idx >> 3, k8 = (idx & 7) << 3;
        const int s = ct + c;                          // source col
        const int dst = (s % 3) * 768 + (s / 192) * 64 + (s % 192) / 3;
        *reinterpret_cast<uint4*>(Wht + (size_t)dst * EMB + kt + k8) =
            *reinterpret_cast<const uint4*>(&Th[c][k8]);
        *reinterpret_cast<uint4*>(Wlt + (size_t)dst * EMB + kt + k8) =
            *reinterpret_cast<const uint4*>(&Tl[c][k8]);
    }
}

// ---------------------------------------------------------------------------
// Q/K GEMM (r18-verified form, BK=32): cols 0..1535 of permuted W. A = X
// inline trunc-split; B = straight uint4 copies; always 3-term MFMA.
// (256,2): inline split needs the 256-VGPR budget (r14 lesson). BK=64
// regressed (r19: LDS 73.7KB + VGPR 116 -> occupancy 16%, 78->86us).
// ---------------------------------------------------------------------------
__global__ __launch_bounds__(256, 2)
void gemm_qk(const float* __restrict__ X,
             const unsigned short* __restrict__ Wht, const unsigned short* __restrict__ Wlt,
             const float* __restrict__ bias,
             unsigned short* __restrict__ Qh, unsigned short* __restrict__ Ql,
             unsigned short* __restrict__ Kh, unsigned short* __restrict__ Kl)
{
    __shared__ unsigned short Ash[128][40], Asl[128][40];  // [row][k]
    __shared__ unsigned short Bsh[128][40], Bsl[128][40];  // [col'][k]

    const int tid  = threadIdx.x;
    const int wave = tid >> 6, lane = tid & 63;
    const int lr = lane & 15, lg = lane >> 4;
    const int wr = (wave >> 1) * 64, wc = (wave & 1) * 64;
    const int m0 = blockIdx.y * 128;
    const int c0 = blockIdx.x * 128;          // 0..1408

    const f32x4 fzero = {0.f, 0.f, 0.f, 0.f};
    f32x4 acc[4][4];
    #pragma unroll
    for (int m = 0; m < 4; ++m)
        #pragma unroll
        for (int n = 0; n < 4; ++n) acc[m][n] = fzero;

    for (int k0 = 0; k0 < EMB; k0 += 32) {
        #pragma unroll
        for (int p = 0; p < 4; ++p) {
            int idx = (p << 8) + tid;
            int row = idx >> 3, kc = (idx & 7) << 2;
            f32x4 v = *reinterpret_cast<const f32x4*>(X + (size_t)(m0 + row) * EMB + k0 + kc);
            float l0 = v[0] - truncbf(v[0]), l1 = v[1] - truncbf(v[1]);
            float l2 = v[2] - truncbf(v[2]), l3 = v[3] - truncbf(v[3]);
            uint2 hw = { packtr(v[0], v[1]), packtr(v[2], v[3]) };
            uint2 lw = { packtr(l0, l1), packtr(l2, l3) };
            *reinterpret_cast<uint2*>(&Ash[row][kc]) = hw;
            *reinterpret_cast<uint2*>(&Asl[row][kc]) = lw;
        }
        #pragma unroll
        for (int p = 0; p < 2; ++p) {
            int idx = (p << 8) + tid;
            int row = idx >> 2, kc = (idx & 3) << 3;
            const size_t boff = (size_t)(c0 + row) * EMB + k0 + kc;
            *reinterpret_cast<uint4*>(&Bsh[row][kc]) = *reinterpret_cast<const uint4*>(Wht + boff);
            *reinterpret_cast<uint4*>(&Bsl[row][kc]) = *reinterpret_cast<const uint4*>(Wlt + boff);
        }
        __syncthreads();

        short8 ah[4], al[4], bh[4], bl[4];
        #pragma unroll
        for (int m = 0; m < 4; ++m) {
            ah[m] = *reinterpret_cast<const short8*>(&Ash[wr + m * 16 + lr][lg << 3]);
            al[m] = *reinterpret_cast<const short8*>(&Asl[wr + m * 16 + lr][lg << 3]);
        }
        #pragma unroll
        for (int n = 0; n < 4; ++n) {
            bh[n] = *reinterpret_cast<const short8*>(&Bsh[wc + n * 16 + lr][lg << 3]);
            bl[n] = *reinterpret_cast<const short8*>(&Bsl[wc + n * 16 + lr][lg << 3]);
        }
        #pragma unroll
        for (int m = 0; m < 4; ++m)
            #pragma unroll
            for (int n = 0; n < 4; ++n) {
                acc[m][n] = MFMA16(ah[m], bh[n], acc[m][n]);
                acc[m][n] = MFMA16(ah[m], bl[n], acc[m][n]);
                acc[m][n] = MFMA16(al[m], bh[n], acc[m][n]);
            }
        __syncthreads();
    }

    const int which = c0 / 768;               // block-uniform
    unsigned short* __restrict__ Ph = (which == 0) ? Qh : Kh;
    unsigned short* __restrict__ Pl = (which == 0) ? Ql : Kl;
    #pragma unroll
    for (int m = 0; m < 4; ++m) {
        #pragma unroll
        for (int n = 0; n < 4; ++n) {
            const int colg = c0 + wc + n * 16 + lr;
            const int hd = colg - which * 768;
            const int h  = hd >> 6;
            const int dd = hd & 63;
            const float bv = bias[192 * h + 3 * dd + which];
            const int rowg0 = m0 + wr + m * 16 + (lg << 2);
            const int bi = rowg0 >> 10, ni0 = rowg0 & (SEQ - 1);
            const int bhid = bi * HEADS + h;
            #pragma unroll
            for (int j = 0; j < 4; ++j) {
                const float val = acc[m][n][j] + bv;
                const size_t oidx = ((size_t)bhid * SEQ + ni0 + j) * HD + dd;
                const uint32_t uv = __float_as_uint(val);
                Ph[oidx] = (unsigned short)(uv >> 16);
                Pl[oidx] = (unsigned short)(__float_as_uint(
                    val - __uint_as_float(uv & 0xFFFF0000u)) >> 16);
            }
        }
    }
}

// ---------------------------------------------------------------------------
// V GEMM (r16..r19-verified, branch-free, 1-term): cols 1536..2303.
// ---------------------------------------------------------------------------
__global__ __launch_bounds__(256, 2)
void gemm_v(const float* __restrict__ X,
            const unsigned short* __restrict__ Wht,
            const float* __restrict__ bias,
            unsigned short* __restrict__ Vt)
{
    __shared__ unsigned short Ash[128][40];
    __shared__ unsigned short Bsh[128][40];

    const int tid  = threadIdx.x;
    const int wave = tid >> 6, lane = tid & 63;
    const int lr = lane & 15, lg = lane >> 4;
    const int wr = (wave >> 1) * 64, wc = (wave & 1) * 64;
    const int m0 = blockIdx.y * 128;
    const int c0 = blockIdx.x * 128;          // 0..640 (local to V region)

    const f32x4 fzero = {0.f, 0.f, 0.f, 0.f};
    f32x4 acc[4][4];
    #pragma unroll
    for (int m = 0; m < 4; ++m)
        #pragma unroll
        for (int n = 0; n < 4; ++n) acc[m][n] = fzero;

    for (int k0 = 0; k0 < EMB; k0 += 32) {
        #pragma unroll
        for (int p = 0; p < 4; ++p) {
            int idx = (p << 8) + tid;
            int row = idx >> 3, kc = (idx & 7) << 2;
            f32x4 v = *reinterpret_cast<const f32x4*>(X + (size_t)(m0 + row) * EMB + k0 + kc);
            uint2 hw = { packtr(v[0], v[1]), packtr(v[2], v[3]) };
            *reinterpret_cast<uint2*>(&Ash[row][kc]) = hw;
        }
        #pragma unroll
        for (int p = 0; p < 2; ++p) {
            int idx = (p << 8) + tid;
            int row = idx >> 2, kc = (idx & 3) << 3;
            const size_t boff = (size_t)(1536 + c0 + row) * EMB + k0 + kc;
            *reinterpret_cast<uint4*>(&Bsh[row][kc]) = *reinterpret_cast<const uint4*>(Wht + boff);
        }
        __syncthreads();

        short8 a[4], b[4];
        #pragma unroll
        for (int m = 0; m < 4; ++m)
            a[m] = *reinterpret_cast<const short8*>(&Ash[wr + m * 16 + lr][lg << 3]);
        #pragma unroll
        for (int n = 0; n < 4; ++n)
            b[n] = *reinterpret_cast<const short8*>(&Bsh[wc + n * 16 + lr][lg << 3]);
        #pragma unroll
        for (int m = 0; m < 4; ++m)
            #pragma unroll
            for (int n = 0; n < 4; ++n)
                acc[m][n] = MFMA16(a[m], b[n], acc[m][n]);
        __syncthreads();
    }

    #pragma unroll
    for (int m = 0; m < 4; ++m) {
        #pragma unroll
        for (int n = 0; n < 4; ++n) {
            const int hd = c0 + wc + n * 16 + lr;     // 0..767
            const int h  = hd >> 6;
            const int dd = hd & 63;
            const float bv = bias[192 * h + 3 * dd + 2];
            const int rowg0 = m0 + wr + m * 16 + (lg << 2);
            const int bi = rowg0 >> 10, ni0 = rowg0 & (SEQ - 1);
            const int bhid = bi * HEADS + h;
            const float v0 = acc[m][n][0] + bv, v1 = acc[m][n][1] + bv;
            const float v2 = acc[m][n][2] + bv, v3 = acc[m][n][3] + bv;
            uint2 w = { (uint32_t)f2bf(v0) | ((uint32_t)f2bf(v1) << 16),
                        (uint32_t)f2bf(v2) | ((uint32_t)f2bf(v3) << 16) };
            *reinterpret_cast<uint2*>(Vt + ((size_t)bhid * HD + dd) * SEQ + ni0) = w;
        }
    }
}

// ---------------------------------------------------------------------------
// Flash attention, QBLK=128 (r19-verified): wave owns TWO 16-row q-groups.
// 768 blocks = exactly 3/CU (no tail); K/V staging amortized 2x; both QK
// MFMA batches issue before softmax-A (VALU/MFMA overlap). Register-prefetch
// staging (r17), cvt_pk + defer-max + max3 softmax (r18).
// ---------------------------------------------------------------------------
__global__ __launch_bounds__(256, 3)
void attn_fused(const unsigned short* __restrict__ Qh, const unsigned short* __restrict__ Ql,
                const unsigned short* __restrict__ Kh, const unsigned short* __restrict__ Kl,
                const unsigned short* __restrict__ Vt,
                unsigned short* __restrict__ Ob)
{
    __shared__ unsigned short Vs[64][72];         // V^T tile: [d][key]
    __shared__ unsigned short Ksh[64][72];        // K hi tile: [key][d]
    __shared__ unsigned short Ksl[64][72];        // K lo tile: [key][d]
    __shared__ unsigned short Plds[2][4][16][72]; // P per group/wave: [qrow][key]

    const int tid  = threadIdx.x;
    const int wave = tid >> 6, lane = tid & 63;
    const int lr = lane & 15, lg = lane >> 4;

    // bijective XCD swizzle: 768 blocks = 8 XCD * 96; same-bh blocks co-locate
    const int bid = blockIdx.x;
    const int lid = (bid & 7) * 96 + (bid >> 3);
    const int qt = lid & 7;             // 0..7
    const int bh = lid >> 3;            // 0..95
    const int b = bh / HEADS, h = bh % HEADS;

    const size_t base = (size_t)bh * SEQ * HD;
    const unsigned short* Qhb = Qh + base;
    const unsigned short* Qlb = Ql + base;
    const unsigned short* Khb = Kh + base;
    const unsigned short* Klb = Kl + base;
    const unsigned short* Vtb = Vt + base;      // [HD][SEQ]

    const int qA = qt * 128 + wave * 16;
    const int qB = qA + 64;

    short8 qhA[2], qlA[2], qhB[2], qlB[2];
    #pragma unroll
    for (int kk = 0; kk < 2; ++kk) {
        const size_t offA = (size_t)(qA + lr) * HD + kk * 32 + (lg << 3);
        const size_t offB = (size_t)(qB + lr) * HD + kk * 32 + (lg << 3);
        qhA[kk] = *reinterpret_cast<const short8*>(Qhb + offA);
        qlA[kk] = *reinterpret_cast<const short8*>(Qlb + offA);
        qhB[kk] = *reinterpret_cast<const short8*>(Qhb + offB);
        qlB[kk] = *reinterpret_cast<const short8*>(Qlb + offB);
    }

    const int r0 = tid >> 3, cs = (tid & 7) << 3;
    const int r1 = r0 + 32;

    uint4 vr0 = *reinterpret_cast<const uint4*>(Vtb + (size_t)r0 * SEQ + cs);
    uint4 vr1 = *reinterpret_cast<const uint4*>(Vtb + (size_t)r1 * SEQ + cs);
    uint4 kh0 = *reinterpret_cast<const uint4*>(Khb + (size_t)r0 * HD + cs);
    uint4 kh1 = *reinterpret_cast<const uint4*>(Khb + (size_t)r1 * HD + cs);
    uint4 kl0 = *reinterpret_cast<const uint4*>(Klb + (size_t)r0 * HD + cs);
    uint4 kl1 = *reinterpret_cast<const uint4*>(Klb + (size_t)r1 * HD + cs);

    float mA = -1.0e30f, lA = 0.f, mB = -1.0e30f, lB = 0.f;
    f32x4 oaccA[4], oaccB[4];
    const f32x4 fzero = {0.f, 0.f, 0.f, 0.f};
    #pragma unroll
    for (int d = 0; d < 4; ++d) { oaccA[d] = fzero; oaccB[d] = fzero; }

    for (int t = 0; t < SEQ / 64; ++t) {
        __syncthreads();
        *reinterpret_cast<uint4*>(&Vs[r0][cs])  = vr0;
        *reinterpret_cast<uint4*>(&Vs[r1][cs])  = vr1;
        *reinterpret_cast<uint4*>(&Ksh[r0][cs]) = kh0;
        *reinterpret_cast<uint4*>(&Ksh[r1][cs]) = kh1;
        *reinterpret_cast<uint4*>(&Ksl[r0][cs]) = kl0;
        *reinterpret_cast<uint4*>(&Ksl[r1][cs]) = kl1;
        __syncthreads();

        if (t < SEQ / 64 - 1) {
            const int kb = (t + 1) * 64;
            vr0 = *reinterpret_cast<const uint4*>(Vtb + (size_t)r0 * SEQ + kb + cs);
            vr1 = *reinterpret_cast<const uint4*>(Vtb + (size_t)r1 * SEQ + kb + cs);
            kh0 = *reinterpret_cast<const uint4*>(Khb + (size_t)(kb + r0) * HD + cs);
            kh1 = *reinterpret_cast<const uint4*>(Khb + (size_t)(kb + r1) * HD + cs);
            kl0 = *reinterpret_cast<const uint4*>(Klb + (size_t)(kb + r0) * HD + cs);
            kl1 = *reinterpret_cast<const uint4*>(Klb + (size_t)(kb + r1) * HD + cs);
        }

        // QK^T for BOTH groups first (softmax-A VALU overlaps sB's MFMAs)
        f32x4 sA[4], sB[4];
        #pragma unroll
        for (int n = 0; n < 4; ++n) { sA[n] = fzero; sB[n] = fzero; }
        #pragma unroll
        for (int n = 0; n < 4; ++n) {
            #pragma unroll
            for (int kk = 0; kk < 2; ++kk) {
                const short8 kh = *reinterpret_cast<const short8*>(&Ksh[n * 16 + lr][kk * 32 + (lg << 3)]);
                const short8 kl = *reinterpret_cast<const short8*>(&Ksl[n * 16 + lr][kk * 32 + (lg << 3)]);
                sA[n] = MFMA16(kh, qhA[kk], sA[n]);
                sA[n] = MFMA16(kh, qlA[kk], sA[n]);
                sA[n] = MFMA16(kl, qhA[kk], sA[n]);
                sB[n] = MFMA16(kh, qhB[kk], sB[n]);
                sB[n] = MFMA16(kh, qlB[kk], sB[n]);
                sB[n] = MFMA16(kl, qhB[kk], sB[n]);
            }
        }

        // ---- softmax + PV, group A ----
        {
            float a0 = fmaxf(fmaxf(sA[0][0], sA[0][1]), sA[0][2]);
            float a1 = fmaxf(fmaxf(sA[0][3], sA[1][0]), sA[1][1]);
            float a2 = fmaxf(fmaxf(sA[1][2], sA[1][3]), sA[2][0]);
            float a3 = fmaxf(fmaxf(sA[2][1], sA[2][2]), sA[2][3]);
            float a4 = fmaxf(fmaxf(sA[3][0], sA[3][1]), sA[3][2]);
            float tmax = fmaxf(fmaxf(fmaxf(a0, a1), a2), fmaxf(fmaxf(a3, a4), sA[3][3]));
            tmax = fmaxf(tmax, __shfl_xor(tmax, 16));
            tmax = fmaxf(tmax, __shfl_xor(tmax, 32));
            if (!__all(tmax <= mA + 8.0f)) {
                const float mnew = fmaxf(mA, tmax);
                const float corr = __expf(mA - mnew);
                mA = mnew;
                lA *= corr;
                #pragma unroll
                for (int j = 0; j < 4; ++j) {
                    const float cj = __shfl(corr, (lg << 2) + j);
                    oaccA[0][j] *= cj; oaccA[1][j] *= cj;
                    oaccA[2][j] *= cj; oaccA[3][j] *= cj;
                }
            }
            float psum = 0.f;
            #pragma unroll
            for (int n = 0; n < 4; ++n) {
                const float p0 = __expf(sA[n][0] - mA), p1 = __expf(sA[n][1] - mA);
                const float p2 = __expf(sA[n][2] - mA), p3 = __expf(sA[n][3] - mA);
                psum += (p0 + p1) + (p2 + p3);
                uint2 w = { cvtpk(p0, p1), cvtpk(p2, p3) };
                *reinterpret_cast<uint2*>(&Plds[0][wave][lr][n * 16 + (lg << 2)]) = w;
            }
            psum += __shfl_xor(psum, 16);
            psum += __shfl_xor(psum, 32);
            lA += psum;
            #pragma unroll
            for (int kk = 0; kk < 2; ++kk) {
                const short8 ap = *reinterpret_cast<const short8*>(&Plds[0][wave][lr][kk * 32 + (lg << 3)]);
                #pragma unroll
                for (int d = 0; d < 4; ++d) {
                    const short8 bv = *reinterpret_cast<const short8*>(&Vs[d * 16 + lr][kk * 32 + (lg << 3)]);
                    oaccA[d] = MFMA16(ap, bv, oaccA[d]);
                }
            }
        }

        // ---- softmax + PV, group B ----
        {
            float a0 = fmaxf(fmaxf(sB[0][0], sB[0][1]), sB[0][2]);
            float a1 = fmaxf(fmaxf(sB[0][3], sB[1][0]), sB[1][1]);
            float a2 = fmaxf(fmaxf(sB[1][2], sB[1][3]), sB[2][0]);
            float a3 = fmaxf(fmaxf(sB[2][1], sB[2][2]), sB[2][3]);
            float a4 = fmaxf(fmaxf(sB[3][0], sB[3][1]), sB[3][2]);
            float tmax = fmaxf(fmaxf(fmaxf(a0, a1), a2), fmaxf(fmaxf(a3, a4), sB[3][3]));
            tmax = fmaxf(tmax, __shfl_xor(tmax, 16));
            tmax = fmaxf(tmax, __shfl_xor(tmax, 32));
            if (!__all(tmax <= mB + 8.0f)) {
                const float mnew = fmaxf(mB, tmax);
                const float corr = __expf(mB - mnew);
                mB = mnew;
                lB *= corr;
                #pragma unroll
                for (int j = 0; j < 4; ++j) {
                    const float cj = __shfl(corr, (lg << 2) + j);
                    oaccB[0][j] *= cj; oaccB[1][j] *= cj;
                    oaccB[2][j] *= cj; oaccB[3][j] *= cj;
                }
            }
            float psum = 0.f;
            #pragma unroll
            for (int n = 0; n < 4; ++n) {
                const float p0 = __expf(sB[n][0] - mB), p1 = __expf(sB[n][1] - mB);
                const float p2 = __expf(sB[n][2] - mB), p3 = __expf(sB[n][3] - mB);
                psum += (p0 + p1) + (p2 + p3);
                uint2 w = { cvtpk(p0, p1), cvtpk(p2, p3) };
                *reinterpret_cast<uint2*>(&Plds[1][wave][lr][n * 16 + (lg << 2)]) = w;
            }
            psum += __shfl_xor(psum, 16);
            psum += __shfl_xor(psum, 32);
            lB += psum;
            #pragma unroll
            for (int kk = 0; kk < 2; ++kk) {
                const short8 ap = *reinterpret_cast<const short8*>(&Plds[1][wave][lr][kk * 32 + (lg << 3)]);
                #pragma unroll
                for (int d = 0; d < 4; ++d) {
                    const short8 bv = *reinterpret_cast<const short8*>(&Vs[d * 16 + lr][kk * 32 + (lg << 3)]);
                    oaccB[d] = MFMA16(ap, bv, oaccB[d]);
                }
            }
        }
    }

    const float rs = 0.036084391824351615f;  // 1/sqrt(768)
    #pragma unroll
    for (int j = 0; j < 4; ++j) {
        const float ljA = __shfl(lA, (lg << 2) + j);
        const float ljB = __shfl(lB, (lg << 2) + j);
        const float scA = rs / ljA;
        const float scB = rs / ljB;
        const int qa = qA + (lg << 2) + j;
        const int qb = qB + (lg << 2) + j;
        #pragma unroll
        for (int d = 0; d < 4; ++d) {
            Ob[((size_t)b * SEQ + qa) * EMB + h * HD + d * 16 + lr] = f2bf(oaccA[d][j] * scA);
            Ob[((size_t)b * SEQ + qb) * EMB + h * HD + d * 16 + lr] = f2bf(oaccB[d][j] * scB);
        }
    }
}

// ---------------------------------------------------------------------------
// Proj GEMM (r16..r19-verified): Ob bf16 @ W_proj (fp32->bf16 RN) + b -> fp32.
// ---------------------------------------------------------------------------
__global__ __launch_bounds__(256, 4)
void gemm_proj(const unsigned short* __restrict__ A, const float* __restrict__ W,
               const float* __restrict__ bias, float* __restrict__ Out)
{
    __shared__ unsigned short As[128][40];
    __shared__ unsigned short Bs[128][40];

    const int tid  = threadIdx.x;
    const int wave = tid >> 6, lane = tid & 63;
    const int lr = lane & 15, lg = lane >> 4;
    const int wr = (wave >> 1) * 64, wc = (wave & 1) * 64;
    const int m0 = blockIdx.y * 128;
    const int c0 = blockIdx.x * 128;

    const f32x4 fzero = {0.f, 0.f, 0.f, 0.f};
    f32x4 acc[4][4];
    #pragma unroll
    for (int m = 0; m < 4; ++m)
        #pragma unroll
        for (int n = 0; n < 4; ++n) acc[m][n] = fzero;

    const int kgB = tid & 7, cgB = tid >> 3;

    for (int k0 = 0; k0 < EMB; k0 += 32) {
        #pragma unroll
        for (int p = 0; p < 2; ++p) {
            int idx = (p << 8) + tid;
            int row = idx >> 2, kc = (idx & 3) << 3;
            uint4 v = *reinterpret_cast<const uint4*>(A + (size_t)(m0 + row) * EMB + k0 + kc);
            *reinterpret_cast<uint4*>(&As[row][kc]) = v;
        }
        {
            f32x4 v[4];
            #pragma unroll
            for (int i = 0; i < 4; ++i)
                v[i] = *reinterpret_cast<const f32x4*>(
                    W + (size_t)(k0 + kgB * 4 + i) * EMB + c0 + cgB * 4);
            #pragma unroll
            for (int j = 0; j < 4; ++j) {
                uint2 w = { (uint32_t)f2bf(v[0][j]) | ((uint32_t)f2bf(v[1][j]) << 16),
                            (uint32_t)f2bf(v[2][j]) | ((uint32_t)f2bf(v[3][j]) << 16) };
                *reinterpret_cast<uint2*>(&Bs[cgB * 4 + j][kgB * 4]) = w;
            }
        }
        __syncthreads();

        short8 a[4], b[4];
        #pragma unroll
        for (int m = 0; m < 4; ++m)
            a[m] = *reinterpret_cast<const short8*>(&As[wr + m * 16 + lr][lg << 3]);
        #pragma unroll
        for (int n = 0; n < 4; ++n)
            b[n] = *reinterpret_cast<const short8*>(&Bs[wc + n * 16 + lr][lg << 3]);
        #pragma unroll
        for (int m = 0; m < 4; ++m)
            #pragma unroll
            for (int n = 0; n < 4; ++n)
                acc[m][n] = MFMA16(a[m], b[n], acc[m][n]);
        __syncthreads();
    }

    #pragma unroll
    for (int m = 0; m < 4; ++m) {
        #pragma unroll
        for (int n = 0; n < 4; ++n) {
            const int colg = c0 + wc + n * 16 + lr;
            const float bv = bias[colg];
            #pragma unroll
            for (int j = 0; j < 4; ++j) {
                const int rowg = m0 + wr + m * 16 + (lg << 2) + j;
                Out[(size_t)rowg * EMB + colg] = acc[m][n][j] + bv;   // fp32 out
            }
        }
    }
}

// ---------------------------------------------------------------------------
extern "C" void kernel_launch(void* const* d_in, const int* in_sizes, int n_in,
                              void* d_out, int out_size, void* d_ws, size_t ws_size,
                              hipStream_t stream)
{
    const float* x     = (const float*)d_in[0];
    const float* Wqkv  = (const float*)d_in[1];
    const float* bqkv  = (const float*)d_in[2];
    const float* Wproj = (const float*)d_in[3];
    const float* bproj = (const float*)d_in[4];
    float* out = (float*)d_out;    // reference output dtype = float32

    const size_t NQ = (size_t)BATCH * HEADS * SEQ * HD;   // 6291456
    const size_t NW = (size_t)EMB * QKV_COLS;             // 1769472

    unsigned short* Qh = (unsigned short*)d_ws;
    unsigned short* Ql = Qh + NQ;
    unsigned short* Kh = Ql + NQ;
    unsigned short* Kl = Kh + NQ;
    unsigned short* Vt = Kl + NQ;                         // [B,H,D,N]
    unsigned short* Ob = Vt + NQ;                         // total 75.5 MB (proven)

    // W prep scratch in the Ob region (7.1 MB of 12.6): consumed by the two
    // QKV GEMMs, later overwritten by attn_fused (sequential stream).
    unsigned short* Wht = Ob;
    unsigned short* Wlt = Wht + NW;

    split_tw<<<dim3(QKV_COLS / 64, EMB / 64), 256, 0, stream>>>(Wqkv, Wht, Wlt);
    gemm_qk<<<dim3(1536 / 128, M_ROWS / 128), 256, 0, stream>>>(
        x, Wht, Wlt, bqkv, Qh, Ql, Kh, Kl);
    gemm_v<<<dim3(768 / 128, M_ROWS / 128), 256, 0, stream>>>(
        x, Wht, bqkv, Vt);
    attn_fused<<<dim3(8 * BATCH * HEADS), 256, 0, stream>>>(Qh, Ql, Kh, Kl, Vt, Ob);
    gemm_proj<<<dim3(EMB / 128, M_ROWS / 128), 256, 0, stream>>>(
        Ob, Wproj, bproj, out);
}